// Round 11
// baseline (6119.292 us; speedup 1.0000x reference)
//
#include <hip/hip_runtime.h>
#include <stdint.h>

#define T_DIM 512
#define B_DIM 64
#define E_DIM 1024
#define H_DIM 1024
#define G_DIM 4096   // 4*H, packed as p = j*4 + gate
#define SBLK 64      // scan blocks (1/CU by LDS; 2-phase pipeline)
#define CPB  64      // packed gate-cols per scan block (= 16 hidden units)

typedef short bf16x8 __attribute__((ext_vector_type(8)));
typedef float f32x4 __attribute__((ext_vector_type(4)));

__device__ __forceinline__ unsigned short f2b(float f){
  union{float f; unsigned u;} v; v.f = f;
  unsigned r = (v.u + 0x7FFFu + ((v.u >> 16) & 1u)) >> 16;  // RNE
  return (unsigned short)r;
}
__device__ __forceinline__ float b2f(unsigned short u){
  union{unsigned u; float f;} v; v.u = ((unsigned)u) << 16; return v.f;
}
__device__ __forceinline__ float fsigmoid(float x){
  return 1.f / (1.f + __expf(-x));
}
__device__ __forceinline__ float ftanh(float x){
  return 2.f / (1.f + __expf(-2.f * x)) - 1.f;
}

// ---- coherent-point (sc0 sc1) vmem helpers; all asm volatile so issue order
// ---- is program order (the vmcnt ledger depends on this).
template<int OFF>
__device__ __forceinline__ bf16x8 ld_h16(const unsigned short* p){
  bf16x8 r;
  asm volatile("global_load_dwordx4 %0, %1, off offset:%2 sc0 sc1"
               : "=v"(r) : "v"(p), "i"(OFF) : "memory");
  return r;
}
__device__ __forceinline__ bf16x8 ld_g16(const unsigned short* p){
  bf16x8 r;
  asm volatile("global_load_dwordx4 %0, %1, off"
               : "=v"(r) : "v"(p) : "memory");
  return r;
}
__device__ __forceinline__ void st_h16(unsigned short* p, bf16x8 v){
  asm volatile("global_store_dwordx4 %0, %1, off sc0 sc1"
               :: "v"(p), "v"(v) : "memory");
}
__device__ __forceinline__ void st_g16(float* p, f32x4 v){
  asm volatile("global_store_dwordx4 %0, %1, off"
               :: "v"(p), "v"(v) : "memory");
}
__device__ __forceinline__ void st_flag(int* p, int v){
  asm volatile("global_store_dword %0, %1, off sc0 sc1"
               :: "v"(p), "v"(v) : "memory");
}
__device__ __forceinline__ int ld_flag_nb(const int* p){
  int r;
  asm volatile("global_load_dword %0, %1, off sc0 sc1"
               : "=v"(r) : "v"(p) : "memory");
  return r;
}

// wait until <=N vmem outstanding; only DS_READ may be scheduled across
// (mask 0x100) — MFMA/VALU/VMEM pinned (rule #18).
#define WAITV(N) \
  asm volatile("s_waitcnt vmcnt(" #N ")" ::: "memory"); \
  __builtin_amdgcn_sched_barrier(0x100);

#define LD16(d0, d1, p0, p1, G) \
  d0[0]=ld_h16<((G)*8+0)*64>(p0); d0[1]=ld_h16<((G)*8+1)*64>(p0); \
  d0[2]=ld_h16<((G)*8+2)*64>(p0); d0[3]=ld_h16<((G)*8+3)*64>(p0); \
  d0[4]=ld_h16<((G)*8+4)*64>(p0); d0[5]=ld_h16<((G)*8+5)*64>(p0); \
  d0[6]=ld_h16<((G)*8+6)*64>(p0); d0[7]=ld_h16<((G)*8+7)*64>(p0); \
  d1[0]=ld_h16<((G)*8+0)*64>(p1); d1[1]=ld_h16<((G)*8+1)*64>(p1); \
  d1[2]=ld_h16<((G)*8+2)*64>(p1); d1[3]=ld_h16<((G)*8+3)*64>(p1); \
  d1[4]=ld_h16<((G)*8+4)*64>(p1); d1[5]=ld_h16<((G)*8+5)*64>(p1); \
  d1[6]=ld_h16<((G)*8+6)*64>(p1); d1[7]=ld_h16<((G)*8+7)*64>(p1);

// 8 kc-steps: 4 B-frags from LDS, each feeds 2 MFMAs (2 A row-tiles) — B reuse x2.
#define MFMA_GRP2(a0, a1, G) \
  { _Pragma("unroll") \
    for (int u = 0; u < 8; ++u){ \
      int kc_ = (G)*8 + u; \
      bf16x8 b0 = *(const bf16x8*)&Wl[((0*32 + kc_)*64 + lane)*8]; \
      bf16x8 b1 = *(const bf16x8*)&Wl[((1*32 + kc_)*64 + lane)*8]; \
      bf16x8 b2 = *(const bf16x8*)&Wl[((2*32 + kc_)*64 + lane)*8]; \
      bf16x8 b3 = *(const bf16x8*)&Wl[((3*32 + kc_)*64 + lane)*8]; \
      acc00 = __builtin_amdgcn_mfma_f32_16x16x32_bf16(a0[u], b0, acc00, 0,0,0); \
      acc01 = __builtin_amdgcn_mfma_f32_16x16x32_bf16(a0[u], b1, acc01, 0,0,0); \
      acc02 = __builtin_amdgcn_mfma_f32_16x16x32_bf16(a0[u], b2, acc02, 0,0,0); \
      acc03 = __builtin_amdgcn_mfma_f32_16x16x32_bf16(a0[u], b3, acc03, 0,0,0); \
      acc10 = __builtin_amdgcn_mfma_f32_16x16x32_bf16(a1[u], b0, acc10, 0,0,0); \
      acc11 = __builtin_amdgcn_mfma_f32_16x16x32_bf16(a1[u], b1, acc11, 0,0,0); \
      acc12 = __builtin_amdgcn_mfma_f32_16x16x32_bf16(a1[u], b2, acc12, 0,0,0); \
      acc13 = __builtin_amdgcn_mfma_f32_16x16x32_bf16(a1[u], b3, acc13, 0,0,0); \
    } }

// ---------------- prep kernels ----------------

__global__ void pack_weights(const float* __restrict__ Wf, const float* __restrict__ Wi,
                             const float* __restrict__ Wo, const float* __restrict__ Wc,
                             const float* __restrict__ bfv, const float* __restrict__ biv,
                             const float* __restrict__ bov, const float* __restrict__ bcv,
                             unsigned short* __restrict__ WxB, unsigned short* __restrict__ WhB,
                             float* __restrict__ biasP){
  int p = blockIdx.x;            // 0..4095
  int j = p >> 2, g = p & 3;
  const float* W    = (g==0)?Wf:(g==1)?Wi:(g==2)?Wo:Wc;
  const float* bsrc = (g==0)?bfv:(g==1)?biv:(g==2)?bov:bcv;
  const float* wrow = W + (size_t)j * 2048;
  int t = threadIdx.x;           // 256 threads, 4 k each
  float4 x = *(const float4*)(wrow + 4*t);
  float4 h = *(const float4*)(wrow + 1024 + 4*t);
  ushort4 xo = make_ushort4(f2b(x.x), f2b(x.y), f2b(x.z), f2b(x.w));
  ushort4 ho = make_ushort4(f2b(h.x), f2b(h.y), f2b(h.z), f2b(h.w));
  *(ushort4*)&WxB[(size_t)p*1024 + 4*t] = xo;
  *(ushort4*)&WhB[(size_t)p*1024 + 4*t] = ho;
  if (t == 0) biasP[p] = bsrc[j];
}

__global__ void conv_emb(const float* __restrict__ emb, unsigned short* __restrict__ embB,
                         size_t n4){
  for (size_t i = (size_t)blockIdx.x * blockDim.x + threadIdx.x; i < n4;
       i += (size_t)gridDim.x * blockDim.x){
    float4 v = ((const float4*)emb)[i];
    ((ushort4*)embB)[i] = make_ushort4(f2b(v.x), f2b(v.y), f2b(v.z), f2b(v.w));
  }
}

__global__ void zero_state(unsigned short* __restrict__ h0, unsigned short* __restrict__ h1,
                           float* __restrict__ c, int* __restrict__ flags){
  int i = blockIdx.x * blockDim.x + threadIdx.x;  // 65536 threads exactly
  h0[i] = 0; h1[i] = 0; c[i] = 0.f;
  if (i < 4096) flags[i] = 0;
}

// ---------------- big GEMM: xg_chunk = embB @ WxB^T (bf16 out) ----------------
__launch_bounds__(256)
__global__ void gemm_xg(const unsigned short* __restrict__ A,
                        const unsigned short* __restrict__ B,
                        unsigned short* __restrict__ C){
  __shared__ unsigned short Al[128*32];
  __shared__ unsigned short Bl[128*32];
  int m0 = blockIdx.x * 128, n0 = blockIdx.y * 128;
  int tid = threadIdx.x, lane = tid & 63, wid = tid >> 6;
  int mblk = (wid >> 1) * 64, nblk = (wid & 1) * 64;
  int rl = lane & 15, kg = lane >> 4;
  f32x4 acc[4][4] = {};

  for (int kk = 0; kk < 1024; kk += 32){
    {
      int c0 = tid, c1 = tid + 256;
      int r = c0 >> 2, g = c0 & 3, s = g ^ ((r >> 1) & 3);
      *(uint4*)&Al[r*32 + s*8] = *(const uint4*)&A[(size_t)(m0 + r)*1024 + kk + g*8];
      *(uint4*)&Bl[r*32 + s*8] = *(const uint4*)&B[(size_t)(n0 + r)*1024 + kk + g*8];
      r = c1 >> 2; g = c1 & 3; s = g ^ ((r >> 1) & 3);
      *(uint4*)&Al[r*32 + s*8] = *(const uint4*)&A[(size_t)(m0 + r)*1024 + kk + g*8];
      *(uint4*)&Bl[r*32 + s*8] = *(const uint4*)&B[(size_t)(n0 + r)*1024 + kk + g*8];
    }
    __syncthreads();
    bf16x8 a[4], b[4];
    #pragma unroll
    for (int mf = 0; mf < 4; ++mf){
      int r = mblk + mf*16 + rl;
      a[mf] = *(const bf16x8*)&Al[r*32 + (kg ^ ((r >> 1) & 3))*8];
    }
    #pragma unroll
    for (int nf = 0; nf < 4; ++nf){
      int r = nblk + nf*16 + rl;
      b[nf] = *(const bf16x8*)&Bl[r*32 + (kg ^ ((r >> 1) & 3))*8];
    }
    #pragma unroll
    for (int mf = 0; mf < 4; ++mf)
      #pragma unroll
      for (int nf = 0; nf < 4; ++nf)
        acc[mf][nf] = __builtin_amdgcn_mfma_f32_16x16x32_bf16(a[mf], b[nf], acc[mf][nf], 0, 0, 0);
    __syncthreads();
  }

  // C/D layout (m89-verified): col = lane&15, row = (lane>>4)*4 + reg
  int rq = kg * 4;
  #pragma unroll
  for (int mf = 0; mf < 4; ++mf)
    #pragma unroll
    for (int nf = 0; nf < 4; ++nf){
      int col = n0 + nblk + nf*16 + rl;
      #pragma unroll
      for (int r = 0; r < 4; ++r){
        int row = m0 + mblk + mf*16 + rq + r;
        C[(size_t)row * G_DIM + col] = f2b(acc[mf][nf][r]);
      }
    }
}

// ---------------- persistent recurrent scan: 2-phase pipeline ----------------
// 64 blocks x 64 threads (1 wave), 1 block/CU (137 KB LDS). Block cs owns
// pcols cs*64..+64 (16 hidden units). Phase g in {0,1} = batch rows g*32..+32
// — the two phases are INDEPENDENT LSTM instances, so phase g's L3 sync
// window hides under phase g^1's compute. Flags discovered via non-blocking
// deferred polls (issued mid-phase, checked at phase end); counted-vmcnt
// ledger spans phase boundaries (all vmem is asm volatile -> program order).
// flag[blk][g] = t+1  <=>  "blk stored h(g,t) (ack'd) AND finished reading
// h(g,t-1)" — same 2-slot ping-pong safety proof as r6.
#define PHASE(G, t)                                                            \
{                                                                              \
  /* entry outstanding: [H 1][xg 4][A32: P,Q][out 2] (H/out absent in         \
     prologue/slow-path variants -- WAITV constants still exact) */           \
  WAITV(18);   /* H + xg4 + A-g0 complete -> safe to publish prev flag */     \
  st_flag(&flags[(cs*2 + ((G)^1))*16], ((G)==0) ? (t) : ((t)+1));              \
  f32x4 acc00={},acc01={},acc02={},acc03={},acc10={},acc11={},acc12={},acc13={};\
  MFMA_GRP2(P0, P1, 0);                                                        \
  LD16(P0, P1, ap0, ap1, 2);   /* current phase, groups 2,3 */                 \
  LD16(R0, R1, ap0, ap1, 3);                                                   \
  pv = ld_flag_nb(&flags[(lane*2 + ((G)^1))*16]);                              \
  WAITV(35);   /* A-g1 complete */                                             \
  MFMA_GRP2(Q0, Q1, 1);                                                        \
  WAITV(17);   /* A-g2 complete */                                             \
  MFMA_GRP2(P0, P1, 2);                                                        \
  WAITV(1);    /* A-g3 complete (poll may linger) */                           \
  MFMA_GRP2(R0, R1, 3);                                                        \
  asm volatile("s_waitcnt lgkmcnt(0)" ::: "memory");                           \
  { int r0 = kg*4;                                                             \
    _Pragma("unroll") for (int rg = 0; rg < 4; ++rg){                          \
      gl[r0+rg][ 0+rl]=acc00[rg]; gl[r0+rg][16+rl]=acc01[rg];                  \
      gl[r0+rg][32+rl]=acc02[rg]; gl[r0+rg][48+rl]=acc03[rg];                  \
      gl[16+r0+rg][ 0+rl]=acc10[rg]; gl[16+r0+rg][16+rl]=acc11[rg];            \
      gl[16+r0+rg][32+rl]=acc12[rg]; gl[16+r0+rg][48+rl]=acc13[rg]; } }        \
  asm volatile("s_waitcnt lgkmcnt(0)" ::: "memory");                           \
  __builtin_amdgcn_sched_barrier(0);                                           \
  union{ unsigned short us[8]; bf16x8 v; } hp;                                 \
  f32x4 ovA, ovB;                                                              \
  _Pragma("unroll") for (int m = 0; m < 8; ++m){                               \
    f32x4 gv = *(const f32x4*)&gl[bb][q*32 + m*4];                             \
    _Pragma("unroll") for (int e = 0; e < 4; ++e)                              \
      gv[e] += b2f((unsigned short)xr[m>>1][(m&1)*4 + e]) + bias8[m][e];       \
    float f_ = fsigmoid(gv[0]), i_ = fsigmoid(gv[1]);                          \
    float o_ = fsigmoid(gv[2]), ct_ = ftanh(gv[3]);                            \
    float c_ = f_*cvs[G][m] + i_*ct_; cvs[G][m] = c_;                          \
    float hn = o_*ftanh(c_);                                                   \
    hp.us[m] = f2b(hn);                                                        \
    if (m < 4) ovA[m] = hn; else ovB[m-4] = hn;                                \
  }                                                                            \
  { unsigned short* hout = ((t)&1) ? hb0 : hb1;                                \
    st_h16(&hout[(size_t)((G)*32 + bb)*H_DIM + cs*16 + q*8], hp.v); }          \
  WAITV(1);    /* poll value landed (H may linger) */                          \
  __builtin_amdgcn_sched_barrier(0);                                           \
  { const int tn = ((G)==0) ? (t) : ((t)+1);                                   \
    if (__any(pv < tn)){   /* slow path: blocking spin (drains vmcnt) */       \
      const int* fp = &flags[(lane*2 + ((G)^1))*16];                           \
      while (__any(__hip_atomic_load(fp, __ATOMIC_RELAXED,                     \
                                     __HIP_MEMORY_SCOPE_AGENT) < tn))          \
        __builtin_amdgcn_s_sleep(1);                                           \
    }                                                                          \
    const unsigned short* hinN = ((tn)&1) ? hb1 : hb0;                         \
    ap0 = hinN + (size_t)((((G)^1)*32) + rl)*1024 + kg*8;                      \
    ap1 = ap0 + (size_t)16*1024;                                               \
    int txg = (tn < t1) ? tn : (t1 - 1);                                       \
    const unsigned short* xgpN = xgc + ((size_t)(txg - t0)*B_DIM               \
        + (((G)^1)*32 + bb))*G_DIM + cs*64 + q*32;                             \
    xr[0] = ld_g16(xgpN);      xr[1] = ld_g16(xgpN + 8);                       \
    xr[2] = ld_g16(xgpN + 16); xr[3] = ld_g16(xgpN + 24);                      \
    LD16(P0, P1, ap0, ap1, 0);                                                 \
    LD16(Q0, Q1, ap0, ap1, 1);                                                 \
    st_g16(&out[((size_t)((G)*32 + bb)*T_DIM + (t))*H_DIM + cs*16 + q*8], ovA);\
    st_g16(&out[((size_t)((G)*32 + bb)*T_DIM + (t))*H_DIM + cs*16 + q*8 + 4], ovB);\
  }                                                                            \
}

__launch_bounds__(64, 1)
__global__ void lstm_scan(const unsigned short* __restrict__ WhB,
                          const unsigned short* __restrict__ xgc,  // bf16 [t1-t0][B][G]
                          const float* __restrict__ biasP,
                          unsigned short* __restrict__ hb0,
                          unsigned short* __restrict__ hb1,
                          float* __restrict__ cglob,
                          float* __restrict__ out,
                          int* __restrict__ flags,
                          int t0, int t1){
  __shared__ unsigned short Wl[4*32*64*8];   // 128 KB frag-major [ct][kc][lane][8]
  __shared__ float gl[32][68];               // 8.7 KB gate staging (+pad)

  const int tid = threadIdx.x;               // 0..63 (one wave)
  const int cs = blockIdx.x;                 // 0..63
  const int lane = tid;
  const int rl = lane & 15, kg = lane >> 4;

  // One-time: stage Wh fragments (A/B share the same (lane,elem)->k map)
  for (int idx = tid; idx < 4*32*64; idx += 64){
    int ct = idx >> 11, kc = (idx >> 6) & 31, l = idx & 63;
    int col = cs*CPB + ct*16 + (l & 15);
    int k   = kc*32 + (l >> 4)*8;
    *(bf16x8*)&Wl[idx*8] = *(const bf16x8*)&WhB[(size_t)col*1024 + k];
  }

  // elementwise mapping: thread -> (local row bb in phase, unit-half q)
  const int bb = tid >> 1, q = tid & 1;      // 8 units: cs*16 + q*8 ..
  f32x4 bias8[8];
  #pragma unroll
  for (int m = 0; m < 8; ++m)
    bias8[m] = *(const f32x4*)&biasP[cs*64 + q*32 + m*4];
  float cvs[2][8];
  #pragma unroll
  for (int g = 0; g < 2; ++g){
    f32x4 lo = *(const f32x4*)&cglob[(size_t)(g*32 + bb)*H_DIM + cs*16 + q*8];
    f32x4 hi = *(const f32x4*)&cglob[(size_t)(g*32 + bb)*H_DIM + cs*16 + q*8 + 4];
    #pragma unroll
    for (int e = 0; e < 4; ++e){ cvs[g][e] = lo[e]; cvs[g][4+e] = hi[e]; }
  }

  __syncthreads();  // Wl staged (also drains all prior vmem)

  // prologue: blocking wait for phase (0, t0)'s producers
  {
    const int* fp = &flags[(lane*2 + 0)*16];
    while (__any(__hip_atomic_load(fp, __ATOMIC_RELAXED,
                                   __HIP_MEMORY_SCOPE_AGENT) < t0))
      __builtin_amdgcn_s_sleep(1);
  }

  // loop-carried state
  bf16x8 P0[8], P1[8], Q0[8], Q1[8], R0[8], R1[8];
  bf16x8 xr[4];
  const unsigned short* ap0;
  const unsigned short* ap1;
  int pv = 0x7FFFFFFF;

  // prologue issues — ledger shape matches steady state: [d1][xg4][A32][d2 d3]
  {
    const unsigned short* hin0 = (t0 & 1) ? hb1 : hb0;
    ap0 = hin0 + (size_t)rl*1024 + kg*8;
    ap1 = ap0 + (size_t)16*1024;
    bf16x8 d1 = ld_g16(xgc);                       // dummy (H slot)
    const unsigned short* xgp0 = xgc + ((size_t)bb)*G_DIM + cs*64 + q*32;
    xr[0] = ld_g16(xgp0);      xr[1] = ld_g16(xgp0 + 8);
    xr[2] = ld_g16(xgp0 + 16); xr[3] = ld_g16(xgp0 + 24);
    LD16(P0, P1, ap0, ap1, 0);
    LD16(Q0, Q1, ap0, ap1, 1);
    bf16x8 d2 = ld_g16(xgc); bf16x8 d3 = ld_g16(xgc + 8);   // dummies (out slots)
    asm volatile("" :: "v"(d1), "v"(d2), "v"(d3));
  }

  for (int t = t0; t < t1; ++t){
    PHASE(0, t);
    PHASE(1, t);
  }

  // epilogue: drain everything, publish final flag for chunk continuity
  WAITV(0);
  st_flag(&flags[(cs*2 + 1)*16], t1);
  #pragma unroll
  for (int g = 0; g < 2; ++g){
    f32x4 lo, hi;
    #pragma unroll
    for (int e = 0; e < 4; ++e){ lo[e] = cvs[g][e]; hi[e] = cvs[g][4+e]; }
    *(f32x4*)&cglob[(size_t)(g*32 + bb)*H_DIM + cs*16 + q*8] = lo;
    *(f32x4*)&cglob[(size_t)(g*32 + bb)*H_DIM + cs*16 + q*8 + 4] = hi;
  }
}

// ---------------- round-1 proven fallback: per-step launched kernel ----------------
__device__ __forceinline__ bf16x8 cvt_f8(const float* p){
  float4 u = *(const float4*)p;
  float4 v = *(const float4*)(p + 4);
  bf16x8 r;
  r[0] = (short)f2b(u.x); r[1] = (short)f2b(u.y); r[2] = (short)f2b(u.z); r[3] = (short)f2b(u.w);
  r[4] = (short)f2b(v.x); r[5] = (short)f2b(v.y); r[6] = (short)f2b(v.z); r[7] = (short)f2b(v.w);
  return r;
}

__launch_bounds__(256)
__global__ void lstm_step(const unsigned short* __restrict__ WhB,
                          const unsigned short* __restrict__ WxB,
                          const float* __restrict__ emb_t,
                          const unsigned short* __restrict__ h_in,
                          unsigned short* __restrict__ h_out,
                          float* __restrict__ cbuf,
                          const float* __restrict__ biasP,
                          float* __restrict__ out, int t){
  __shared__ float glds[64 * 17];
  int tid = threadIdx.x, lane = tid & 63, w = tid >> 6;
  int blk = blockIdx.x;
  int rl = lane & 15, kg = lane >> 4;
  int arow = w * 16 + rl;
  int pcol = blk * 16 + rl;

  f32x4 acc0 = {}, acc1 = {};
  const unsigned short* hrow = h_in + (size_t)arow * 1024 + kg * 8;
  const unsigned short* wrow = WhB + (size_t)pcol * 1024 + kg * 8;
  #pragma unroll 4
  for (int kk = 0; kk < 1024; kk += 64){
    bf16x8 a0 = *(const bf16x8*)(hrow + kk);
    bf16x8 b0 = *(const bf16x8*)(wrow + kk);
    bf16x8 a1 = *(const bf16x8*)(hrow + kk + 32);
    bf16x8 b1 = *(const bf16x8*)(wrow + kk + 32);
    acc0 = __builtin_amdgcn_mfma_f32_16x16x32_bf16(a0, b0, acc0, 0, 0, 0);
    acc1 = __builtin_amdgcn_mfma_f32_16x16x32_bf16(a1, b1, acc1, 0, 0, 0);
  }
  {
    const float* xrow = emb_t + (size_t)arow * 1024 + kg * 8;
    const unsigned short* wxrow = WxB + (size_t)pcol * 1024 + kg * 8;
    #pragma unroll 4
    for (int kk = 0; kk < 1024; kk += 64){
      bf16x8 a0 = cvt_f8(xrow + kk);
      bf16x8 b0 = *(const bf16x8*)(wxrow + kk);
      bf16x8 a1 = cvt_f8(xrow + kk + 32);
      bf16x8 b1 = *(const bf16x8*)(wxrow + kk + 32);
      acc0 = __builtin_amdgcn_mfma_f32_16x16x32_bf16(a0, b0, acc0, 0, 0, 0);
      acc1 = __builtin_amdgcn_mfma_f32_16x16x32_bf16(a1, b1, acc1, 0, 0, 0);
    }
  }
  f32x4 acc = acc0 + acc1;

  #pragma unroll
  for (int r = 0; r < 4; ++r){
    int brow = w * 16 + kg * 4 + r;
    glds[brow * 17 + rl] = acc[r];
  }
  __syncthreads();

  int b = tid >> 2, jj = tid & 3;
  int j = blk * 4 + jj;
  int pbase = blk * 16 + jj * 4;
  float gf = glds[b*17 + jj*4 + 0] + biasP[pbase + 0];
  float gi = glds[b*17 + jj*4 + 1] + biasP[pbase + 1];
  float go = glds[b*17 + jj*4 + 2] + biasP[pbase + 2];
  float gc = glds[b*17 + jj*4 + 3] + biasP[pbase + 3];
  float f  = fsigmoid(gf);
  float i_ = fsigmoid(gi);
  float o  = fsigmoid(go);
  float ct = ftanh(gc);
  float c_old = cbuf[b * H_DIM + j];
  float cn = f * c_old + i_ * ct;
  float hn = o * ftanh(cn);
  cbuf[b * H_DIM + j] = cn;
  h_out[b * H_DIM + j] = f2b(hn);
  out[((size_t)b * T_DIM + t) * H_DIM + j] = hn;
}

// ---------------- launch ----------------
extern "C" void kernel_launch(void* const* d_in, const int* in_sizes, int n_in,
                              void* d_out, int out_size, void* d_ws, size_t ws_size,
                              hipStream_t stream){
  (void)in_sizes; (void)n_in; (void)out_size;
  const float* emb = (const float*)d_in[0];
  const float* Wf  = (const float*)d_in[1];
  const float* bfv = (const float*)d_in[2];
  const float* Wi  = (const float*)d_in[3];
  const float* biv = (const float*)d_in[4];
  const float* Wo  = (const float*)d_in[5];
  const float* bov = (const float*)d_in[6];
  const float* Wc  = (const float*)d_in[7];
  const float* bcv = (const float*)d_in[8];
  float* out = (float*)d_out;

  char* ws = (char*)d_ws;
  size_t off = 0;
  auto alloc = [&](size_t bytes) -> void* {
    void* p = ws + off; off += (bytes + 255) & ~(size_t)255; return p;
  };
  unsigned short* WxB   = (unsigned short*)alloc((size_t)G_DIM * 1024 * 2);
  unsigned short* WhB   = (unsigned short*)alloc((size_t)G_DIM * 1024 * 2);
  float*          biasP = (float*)alloc((size_t)G_DIM * 4);
  unsigned short* h0    = (unsigned short*)alloc((size_t)B_DIM * H_DIM * 2);
  unsigned short* h1    = (unsigned short*)alloc((size_t)B_DIM * H_DIM * 2);
  float*          cglob = (float*)alloc((size_t)B_DIM * H_DIM * 4);
  int*            flags = (int*)alloc((size_t)4096 * 4);
  size_t base_end = off;

  // choose largest T-chunk whose embB(bf16) + xg(bf16) buffers fit in d_ws
  int Tc = 0;
  const int cands[6] = {512, 256, 128, 64, 32, 16};
  for (int ci = 0; ci < 6; ++ci){
    size_t need = base_end
                + (size_t)cands[ci] * B_DIM * E_DIM * 2   // embB chunk
                + (size_t)cands[ci] * B_DIM * G_DIM * 2   // xg chunk (bf16)
                + 4096;
    if (ws_size >= need){ Tc = cands[ci]; break; }
  }
  unsigned short* embB = nullptr;
  unsigned short* xgc  = nullptr;
  if (Tc > 0){
    embB = (unsigned short*)alloc((size_t)Tc * B_DIM * E_DIM * 2);
    xgc  = (unsigned short*)alloc((size_t)Tc * B_DIM * G_DIM * 2);
  }

  pack_weights<<<G_DIM, 256, 0, stream>>>(Wf, Wi, Wo, Wc, bfv, biv, bov, bcv, WxB, WhB, biasP);
  zero_state<<<256, 256, 0, stream>>>(h0, h1, cglob, flags);

  if (Tc > 0){
    for (int t0 = 0; t0 < T_DIM; t0 += Tc){
      conv_emb<<<2048, 256, 0, stream>>>(emb + (size_t)t0 * B_DIM * E_DIM, embB,
                                         (size_t)Tc * B_DIM * E_DIM / 4);
      gemm_xg<<<dim3(Tc * B_DIM / 128, G_DIM / 128), 256, 0, stream>>>(embB, WxB, xgc);
      lstm_scan<<<SBLK, 64, 0, stream>>>(WhB, xgc, biasP, h0, h1, cglob, out,
                                         flags, t0, t0 + Tc);
    }
  } else {
    // round-1 proven fallback: fused per-step kernels (no big buffers needed)
    for (int t = 0; t < T_DIM; ++t){
      const unsigned short* hin = (t & 1) ? h1 : h0;
      unsigned short*      hout = (t & 1) ? h0 : h1;
      lstm_step<<<256, 256, 0, stream>>>(
          WhB, WxB, emb + (size_t)t * B_DIM * E_DIM, hin, hout, cglob, biasP, out, t);
    }
  }
}

// Round 12
// 6110.580 us; speedup vs baseline: 1.0014x; 1.0014x over previous
//
#include <hip/hip_runtime.h>
#include <stdint.h>

#define T_DIM 512
#define B_DIM 64
#define E_DIM 1024
#define H_DIM 1024
#define G_DIM 4096   // 4*H, packed as p = j*4 + gate
#define SBLK 64      // scan blocks (1/CU by LDS; 2-phase pipeline)
#define CPB  64      // packed gate-cols per scan block (= 16 hidden units)

typedef short bf16x8 __attribute__((ext_vector_type(8)));
typedef float f32x4 __attribute__((ext_vector_type(4)));

__device__ __forceinline__ unsigned short f2b(float f){
  union{float f; unsigned u;} v; v.f = f;
  unsigned r = (v.u + 0x7FFFu + ((v.u >> 16) & 1u)) >> 16;  // RNE
  return (unsigned short)r;
}
__device__ __forceinline__ float b2f(unsigned short u){
  union{unsigned u; float f;} v; v.u = ((unsigned)u) << 16; return v.f;
}
__device__ __forceinline__ float fsigmoid(float x){
  return 1.f / (1.f + __expf(-x));
}
__device__ __forceinline__ float ftanh(float x){
  return 2.f / (1.f + __expf(-2.f * x)) - 1.f;
}

// ---- coherent-point (sc0 sc1) vmem helpers; all asm volatile so issue order
// ---- is program order (the vmcnt ledger depends on this).
template<int OFF>
__device__ __forceinline__ bf16x8 ld_h16(const unsigned short* p){
  bf16x8 r;
  asm volatile("global_load_dwordx4 %0, %1, off offset:%2 sc0 sc1"
               : "=v"(r) : "v"(p), "i"(OFF) : "memory");
  return r;
}
__device__ __forceinline__ bf16x8 ld_g16(const unsigned short* p){
  bf16x8 r;
  asm volatile("global_load_dwordx4 %0, %1, off"
               : "=v"(r) : "v"(p) : "memory");
  return r;
}
__device__ __forceinline__ void st_h16(unsigned short* p, bf16x8 v){
  asm volatile("global_store_dwordx4 %0, %1, off sc0 sc1"
               :: "v"(p), "v"(v) : "memory");
}
__device__ __forceinline__ void st_g16(float* p, f32x4 v){
  asm volatile("global_store_dwordx4 %0, %1, off"
               :: "v"(p), "v"(v) : "memory");
}
__device__ __forceinline__ void st_flag(int* p, int v){
  asm volatile("global_store_dword %0, %1, off sc0 sc1"
               :: "v"(p), "v"(v) : "memory");
}
__device__ __forceinline__ int ld_flag_nb(const int* p){
  int r;
  asm volatile("global_load_dword %0, %1, off sc0 sc1"
               : "=v"(r) : "v"(p) : "memory");
  return r;
}

// wait until <=N vmem outstanding; only DS_READ may be scheduled across
// (mask 0x100) — MFMA/VALU/VMEM pinned (rule #18).
#define WAITV(N) \
  asm volatile("s_waitcnt vmcnt(" #N ")" ::: "memory"); \
  __builtin_amdgcn_sched_barrier(0x100);

#define LD16(d0, d1, p0, p1, G) \
  d0[0]=ld_h16<((G)*8+0)*64>(p0); d0[1]=ld_h16<((G)*8+1)*64>(p0); \
  d0[2]=ld_h16<((G)*8+2)*64>(p0); d0[3]=ld_h16<((G)*8+3)*64>(p0); \
  d0[4]=ld_h16<((G)*8+4)*64>(p0); d0[5]=ld_h16<((G)*8+5)*64>(p0); \
  d0[6]=ld_h16<((G)*8+6)*64>(p0); d0[7]=ld_h16<((G)*8+7)*64>(p0); \
  d1[0]=ld_h16<((G)*8+0)*64>(p1); d1[1]=ld_h16<((G)*8+1)*64>(p1); \
  d1[2]=ld_h16<((G)*8+2)*64>(p1); d1[3]=ld_h16<((G)*8+3)*64>(p1); \
  d1[4]=ld_h16<((G)*8+4)*64>(p1); d1[5]=ld_h16<((G)*8+5)*64>(p1); \
  d1[6]=ld_h16<((G)*8+6)*64>(p1); d1[7]=ld_h16<((G)*8+7)*64>(p1);

// 8 kc-steps: 4 B-frags from LDS, each feeds 2 MFMAs (2 A row-tiles) — B reuse x2.
#define MFMA_GRP2(a0, a1, G) \
  { _Pragma("unroll") \
    for (int u = 0; u < 8; ++u){ \
      int kc_ = (G)*8 + u; \
      bf16x8 b0 = *(const bf16x8*)&Wl[((0*32 + kc_)*64 + lane)*8]; \
      bf16x8 b1 = *(const bf16x8*)&Wl[((1*32 + kc_)*64 + lane)*8]; \
      bf16x8 b2 = *(const bf16x8*)&Wl[((2*32 + kc_)*64 + lane)*8]; \
      bf16x8 b3 = *(const bf16x8*)&Wl[((3*32 + kc_)*64 + lane)*8]; \
      acc00 = __builtin_amdgcn_mfma_f32_16x16x32_bf16(a0[u], b0, acc00, 0,0,0); \
      acc01 = __builtin_amdgcn_mfma_f32_16x16x32_bf16(a0[u], b1, acc01, 0,0,0); \
      acc02 = __builtin_amdgcn_mfma_f32_16x16x32_bf16(a0[u], b2, acc02, 0,0,0); \
      acc03 = __builtin_amdgcn_mfma_f32_16x16x32_bf16(a0[u], b3, acc03, 0,0,0); \
      acc10 = __builtin_amdgcn_mfma_f32_16x16x32_bf16(a1[u], b0, acc10, 0,0,0); \
      acc11 = __builtin_amdgcn_mfma_f32_16x16x32_bf16(a1[u], b1, acc11, 0,0,0); \
      acc12 = __builtin_amdgcn_mfma_f32_16x16x32_bf16(a1[u], b2, acc12, 0,0,0); \
      acc13 = __builtin_amdgcn_mfma_f32_16x16x32_bf16(a1[u], b3, acc13, 0,0,0); \
    } }

// ---------------- prep kernels ----------------

__global__ void pack_weights(const float* __restrict__ Wf, const float* __restrict__ Wi,
                             const float* __restrict__ Wo, const float* __restrict__ Wc,
                             const float* __restrict__ bfv, const float* __restrict__ biv,
                             const float* __restrict__ bov, const float* __restrict__ bcv,
                             unsigned short* __restrict__ WxB, unsigned short* __restrict__ WhB,
                             float* __restrict__ biasP){
  int p = blockIdx.x;            // 0..4095
  int j = p >> 2, g = p & 3;
  const float* W    = (g==0)?Wf:(g==1)?Wi:(g==2)?Wo:Wc;
  const float* bsrc = (g==0)?bfv:(g==1)?biv:(g==2)?bov:bcv;
  const float* wrow = W + (size_t)j * 2048;
  int t = threadIdx.x;           // 256 threads, 4 k each
  float4 x = *(const float4*)(wrow + 4*t);
  float4 h = *(const float4*)(wrow + 1024 + 4*t);
  ushort4 xo = make_ushort4(f2b(x.x), f2b(x.y), f2b(x.z), f2b(x.w));
  ushort4 ho = make_ushort4(f2b(h.x), f2b(h.y), f2b(h.z), f2b(h.w));
  *(ushort4*)&WxB[(size_t)p*1024 + 4*t] = xo;
  *(ushort4*)&WhB[(size_t)p*1024 + 4*t] = ho;
  if (t == 0) biasP[p] = bsrc[j];
}

__global__ void conv_emb(const float* __restrict__ emb, unsigned short* __restrict__ embB,
                         size_t n4){
  for (size_t i = (size_t)blockIdx.x * blockDim.x + threadIdx.x; i < n4;
       i += (size_t)gridDim.x * blockDim.x){
    float4 v = ((const float4*)emb)[i];
    ((ushort4*)embB)[i] = make_ushort4(f2b(v.x), f2b(v.y), f2b(v.z), f2b(v.w));
  }
}

__global__ void zero_state(unsigned short* __restrict__ h0, unsigned short* __restrict__ h1,
                           float* __restrict__ c, int* __restrict__ flags){
  int i = blockIdx.x * blockDim.x + threadIdx.x;  // 65536 threads exactly
  h0[i] = 0; h1[i] = 0; c[i] = 0.f;
  if (i < 4096) flags[i] = 0;
}

// ---------------- big GEMM: xg_chunk = embB @ WxB^T (bf16 out) ----------------
__launch_bounds__(256)
__global__ void gemm_xg(const unsigned short* __restrict__ A,
                        const unsigned short* __restrict__ B,
                        unsigned short* __restrict__ C){
  __shared__ unsigned short Al[128*32];
  __shared__ unsigned short Bl[128*32];
  int m0 = blockIdx.x * 128, n0 = blockIdx.y * 128;
  int tid = threadIdx.x, lane = tid & 63, wid = tid >> 6;
  int mblk = (wid >> 1) * 64, nblk = (wid & 1) * 64;
  int rl = lane & 15, kg = lane >> 4;
  f32x4 acc[4][4] = {};

  for (int kk = 0; kk < 1024; kk += 32){
    {
      int c0 = tid, c1 = tid + 256;
      int r = c0 >> 2, g = c0 & 3, s = g ^ ((r >> 1) & 3);
      *(uint4*)&Al[r*32 + s*8] = *(const uint4*)&A[(size_t)(m0 + r)*1024 + kk + g*8];
      *(uint4*)&Bl[r*32 + s*8] = *(const uint4*)&B[(size_t)(n0 + r)*1024 + kk + g*8];
      r = c1 >> 2; g = c1 & 3; s = g ^ ((r >> 1) & 3);
      *(uint4*)&Al[r*32 + s*8] = *(const uint4*)&A[(size_t)(m0 + r)*1024 + kk + g*8];
      *(uint4*)&Bl[r*32 + s*8] = *(const uint4*)&B[(size_t)(n0 + r)*1024 + kk + g*8];
    }
    __syncthreads();
    bf16x8 a[4], b[4];
    #pragma unroll
    for (int mf = 0; mf < 4; ++mf){
      int r = mblk + mf*16 + rl;
      a[mf] = *(const bf16x8*)&Al[r*32 + (kg ^ ((r >> 1) & 3))*8];
    }
    #pragma unroll
    for (int nf = 0; nf < 4; ++nf){
      int r = nblk + nf*16 + rl;
      b[nf] = *(const bf16x8*)&Bl[r*32 + (kg ^ ((r >> 1) & 3))*8];
    }
    #pragma unroll
    for (int mf = 0; mf < 4; ++mf)
      #pragma unroll
      for (int nf = 0; nf < 4; ++nf)
        acc[mf][nf] = __builtin_amdgcn_mfma_f32_16x16x32_bf16(a[mf], b[nf], acc[mf][nf], 0, 0, 0);
    __syncthreads();
  }

  // C/D layout (m89-verified): col = lane&15, row = (lane>>4)*4 + reg
  int rq = kg * 4;
  #pragma unroll
  for (int mf = 0; mf < 4; ++mf)
    #pragma unroll
    for (int nf = 0; nf < 4; ++nf){
      int col = n0 + nblk + nf*16 + rl;
      #pragma unroll
      for (int r = 0; r < 4; ++r){
        int row = m0 + mblk + mf*16 + rq + r;
        C[(size_t)row * G_DIM + col] = f2b(acc[mf][nf][r]);
      }
    }
}

// ---------------- persistent recurrent scan: 2-phase pipeline ----------------
// 64 blocks x 64 threads (1 wave), 1 block/CU (137 KB LDS). Block cs owns
// pcols cs*64..+64 (16 hidden units). Phase g in {0,1} = batch rows g*32..+32
// — the two phases are INDEPENDENT LSTM instances, so phase g's L3 sync
// window hides under phase g^1's compute. Flags discovered via non-blocking
// deferred polls (issued mid-phase, checked at phase end); counted-vmcnt
// ledger spans phase boundaries (all vmem is asm volatile -> program order).
// flag[blk][g] = t+1  <=>  "blk stored h(g,t) (ack'd) AND finished reading
// h(g,t-1)" — same 2-slot ping-pong safety proof as r6.
#define PHASE(G, t)                                                            \
{                                                                              \
  /* entry outstanding: [H 1][xg 4][A32: P,Q][out 2] (H/out absent in         \
     prologue/slow-path variants -- WAITV constants still exact) */           \
  WAITV(18);   /* H + xg4 + A-g0 complete -> safe to publish prev flag */     \
  st_flag(&flags[(cs*2 + ((G)^1))*16], ((G)==0) ? (t) : ((t)+1));              \
  f32x4 acc00={},acc01={},acc02={},acc03={},acc10={},acc11={},acc12={},acc13={};\
  MFMA_GRP2(P0, P1, 0);                                                        \
  LD16(P0, P1, ap0, ap1, 2);   /* current phase, groups 2,3 */                 \
  LD16(R0, R1, ap0, ap1, 3);                                                   \
  pv = ld_flag_nb(&flags[(lane*2 + ((G)^1))*16]);                              \
  WAITV(35);   /* A-g1 complete */                                             \
  MFMA_GRP2(Q0, Q1, 1);                                                        \
  WAITV(17);   /* A-g2 complete */                                             \
  MFMA_GRP2(P0, P1, 2);                                                        \
  WAITV(1);    /* A-g3 complete (poll may linger) */                           \
  MFMA_GRP2(R0, R1, 3);                                                        \
  asm volatile("s_waitcnt lgkmcnt(0)" ::: "memory");                           \
  { int r0 = kg*4;                                                             \
    _Pragma("unroll") for (int rg = 0; rg < 4; ++rg){                          \
      gl[r0+rg][ 0+rl]=acc00[rg]; gl[r0+rg][16+rl]=acc01[rg];                  \
      gl[r0+rg][32+rl]=acc02[rg]; gl[r0+rg][48+rl]=acc03[rg];                  \
      gl[16+r0+rg][ 0+rl]=acc10[rg]; gl[16+r0+rg][16+rl]=acc11[rg];            \
      gl[16+r0+rg][32+rl]=acc12[rg]; gl[16+r0+rg][48+rl]=acc13[rg]; } }        \
  asm volatile("s_waitcnt lgkmcnt(0)" ::: "memory");                           \
  __builtin_amdgcn_sched_barrier(0);                                           \
  union{ unsigned short us[8]; bf16x8 v; } hp;                                 \
  f32x4 ovA, ovB;                                                              \
  _Pragma("unroll") for (int m = 0; m < 8; ++m){                               \
    f32x4 gv = *(const f32x4*)&gl[bb][q*32 + m*4];                             \
    _Pragma("unroll") for (int e = 0; e < 4; ++e)                              \
      gv[e] += b2f((unsigned short)xr[m>>1][(m&1)*4 + e]) + bias8[m][e];       \
    float f_ = fsigmoid(gv[0]), i_ = fsigmoid(gv[1]);                          \
    float o_ = fsigmoid(gv[2]), ct_ = ftanh(gv[3]);                            \
    float c_ = f_*cvs[G][m] + i_*ct_; cvs[G][m] = c_;                          \
    float hn = o_*ftanh(c_);                                                   \
    hp.us[m] = f2b(hn);                                                        \
    if (m < 4) ovA[m] = hn; else ovB[m-4] = hn;                                \
  }                                                                            \
  { unsigned short* hout = ((t)&1) ? hb0 : hb1;                                \
    st_h16(&hout[(size_t)((G)*32 + bb)*H_DIM + cs*16 + q*8], hp.v); }          \
  WAITV(1);    /* poll value landed (H may linger) */                          \
  __builtin_amdgcn_sched_barrier(0);                                           \
  { const int tn = ((G)==0) ? (t) : ((t)+1);                                   \
    if (__any(pv < tn)){   /* slow path: blocking spin (drains vmcnt) */       \
      const int* fp = &flags[(lane*2 + ((G)^1))*16];                           \
      while (__any(__hip_atomic_load(fp, __ATOMIC_RELAXED,                     \
                                     __HIP_MEMORY_SCOPE_AGENT) < tn))          \
        __builtin_amdgcn_s_sleep(1);                                           \
    }                                                                          \
    const unsigned short* hinN = ((tn)&1) ? hb1 : hb0;                         \
    ap0 = hinN + (size_t)((((G)^1)*32) + rl)*1024 + kg*8;                      \
    ap1 = ap0 + (size_t)16*1024;                                               \
    int txg = (tn < t1) ? tn : (t1 - 1);                                       \
    const unsigned short* xgpN = xgc + ((size_t)(txg - t0)*B_DIM               \
        + (((G)^1)*32 + bb))*G_DIM + cs*64 + q*32;                             \
    xr[0] = ld_g16(xgpN);      xr[1] = ld_g16(xgpN + 8);                       \
    xr[2] = ld_g16(xgpN + 16); xr[3] = ld_g16(xgpN + 24);                      \
    LD16(P0, P1, ap0, ap1, 0);                                                 \
    LD16(Q0, Q1, ap0, ap1, 1);                                                 \
    st_g16(&out[((size_t)((G)*32 + bb)*T_DIM + (t))*H_DIM + cs*16 + q*8], ovA);\
    st_g16(&out[((size_t)((G)*32 + bb)*T_DIM + (t))*H_DIM + cs*16 + q*8 + 4], ovB);\
  }                                                                            \
}

__launch_bounds__(64, 1)
__global__ void lstm_scan(const unsigned short* __restrict__ WhB,
                          const unsigned short* __restrict__ xgc,  // bf16 [t1-t0][B][G]
                          const float* __restrict__ biasP,
                          unsigned short* __restrict__ hb0,
                          unsigned short* __restrict__ hb1,
                          float* __restrict__ cglob,
                          float* __restrict__ out,
                          int* __restrict__ flags,
                          int t0, int t1){
  __shared__ unsigned short Wl[4*32*64*8];   // 128 KB frag-major [ct][kc][lane][8]
  __shared__ float gl[32][68];               // 8.7 KB gate staging (+pad)

  const int tid = threadIdx.x;               // 0..63 (one wave)
  const int cs = blockIdx.x;                 // 0..63
  const int lane = tid;
  const int rl = lane & 15, kg = lane >> 4;

  // One-time: stage Wh fragments (A/B share the same (lane,elem)->k map)
  for (int idx = tid; idx < 4*32*64; idx += 64){
    int ct = idx >> 11, kc = (idx >> 6) & 31, l = idx & 63;
    int col = cs*CPB + ct*16 + (l & 15);
    int k   = kc*32 + (l >> 4)*8;
    *(bf16x8*)&Wl[idx*8] = *(const bf16x8*)&WhB[(size_t)col*1024 + k];
  }

  // elementwise mapping: thread -> (local row bb in phase, unit-half q)
  const int bb = tid >> 1, q = tid & 1;      // 8 units: cs*16 + q*8 ..
  f32x4 bias8[8];
  #pragma unroll
  for (int m = 0; m < 8; ++m)
    bias8[m] = *(const f32x4*)&biasP[cs*64 + q*32 + m*4];
  float cvs[2][8];
  #pragma unroll
  for (int g = 0; g < 2; ++g){
    f32x4 lo = *(const f32x4*)&cglob[(size_t)(g*32 + bb)*H_DIM + cs*16 + q*8];
    f32x4 hi = *(const f32x4*)&cglob[(size_t)(g*32 + bb)*H_DIM + cs*16 + q*8 + 4];
    #pragma unroll
    for (int e = 0; e < 4; ++e){ cvs[g][e] = lo[e]; cvs[g][4+e] = hi[e]; }
  }

  __syncthreads();  // Wl staged (also drains all prior vmem)

  // prologue: blocking wait for phase (0, t0)'s producers
  {
    const int* fp = &flags[(lane*2 + 0)*16];
    while (__any(__hip_atomic_load(fp, __ATOMIC_RELAXED,
                                   __HIP_MEMORY_SCOPE_AGENT) < t0))
      __builtin_amdgcn_s_sleep(1);
  }

  // loop-carried state
  bf16x8 P0[8], P1[8], Q0[8], Q1[8], R0[8], R1[8];
  bf16x8 xr[4];
  const unsigned short* ap0;
  const unsigned short* ap1;
  int pv = 0x7FFFFFFF;

  // prologue issues — ledger shape matches steady state: [d1][xg4][A32][d2 d3]
  {
    const unsigned short* hin0 = (t0 & 1) ? hb1 : hb0;
    ap0 = hin0 + (size_t)rl*1024 + kg*8;
    ap1 = ap0 + (size_t)16*1024;
    bf16x8 d1 = ld_g16(xgc);                       // dummy (H slot)
    const unsigned short* xgp0 = xgc + ((size_t)bb)*G_DIM + cs*64 + q*32;
    xr[0] = ld_g16(xgp0);      xr[1] = ld_g16(xgp0 + 8);
    xr[2] = ld_g16(xgp0 + 16); xr[3] = ld_g16(xgp0 + 24);
    LD16(P0, P1, ap0, ap1, 0);
    LD16(Q0, Q1, ap0, ap1, 1);
    bf16x8 d2 = ld_g16(xgc); bf16x8 d3 = ld_g16(xgc + 8);   // dummies (out slots)
    asm volatile("" :: "v"(d1), "v"(d2), "v"(d3));
  }

  for (int t = t0; t < t1; ++t){
    PHASE(0, t);
    PHASE(1, t);
  }

  // epilogue: drain everything, publish final flag for chunk continuity
  WAITV(0);
  st_flag(&flags[(cs*2 + 1)*16], t1);
  #pragma unroll
  for (int g = 0; g < 2; ++g){
    f32x4 lo, hi;
    #pragma unroll
    for (int e = 0; e < 4; ++e){ lo[e] = cvs[g][e]; hi[e] = cvs[g][4+e]; }
    *(f32x4*)&cglob[(size_t)(g*32 + bb)*H_DIM + cs*16 + q*8] = lo;
    *(f32x4*)&cglob[(size_t)(g*32 + bb)*H_DIM + cs*16 + q*8 + 4] = hi;
  }
}

// ---------------- round-1 proven fallback: per-step launched kernel ----------------
__device__ __forceinline__ bf16x8 cvt_f8(const float* p){
  float4 u = *(const float4*)p;
  float4 v = *(const float4*)(p + 4);
  bf16x8 r;
  r[0] = (short)f2b(u.x); r[1] = (short)f2b(u.y); r[2] = (short)f2b(u.z); r[3] = (short)f2b(u.w);
  r[4] = (short)f2b(v.x); r[5] = (short)f2b(v.y); r[6] = (short)f2b(v.z); r[7] = (short)f2b(v.w);
  return r;
}

__launch_bounds__(256)
__global__ void lstm_step(const unsigned short* __restrict__ WhB,
                          const unsigned short* __restrict__ WxB,
                          const float* __restrict__ emb_t,
                          const unsigned short* __restrict__ h_in,
                          unsigned short* __restrict__ h_out,
                          float* __restrict__ cbuf,
                          const float* __restrict__ biasP,
                          float* __restrict__ out, int t){
  __shared__ float glds[64 * 17];
  int tid = threadIdx.x, lane = tid & 63, w = tid >> 6;
  int blk = blockIdx.x;
  int rl = lane & 15, kg = lane >> 4;
  int arow = w * 16 + rl;
  int pcol = blk * 16 + rl;

  f32x4 acc0 = {}, acc1 = {};
  const unsigned short* hrow = h_in + (size_t)arow * 1024 + kg * 8;
  const unsigned short* wrow = WhB + (size_t)pcol * 1024 + kg * 8;
  #pragma unroll 4
  for (int kk = 0; kk < 1024; kk += 64){
    bf16x8 a0 = *(const bf16x8*)(hrow + kk);
    bf16x8 b0 = *(const bf16x8*)(wrow + kk);
    bf16x8 a1 = *(const bf16x8*)(hrow + kk + 32);
    bf16x8 b1 = *(const bf16x8*)(wrow + kk + 32);
    acc0 = __builtin_amdgcn_mfma_f32_16x16x32_bf16(a0, b0, acc0, 0, 0, 0);
    acc1 = __builtin_amdgcn_mfma_f32_16x16x32_bf16(a1, b1, acc1, 0, 0, 0);
  }
  {
    const float* xrow = emb_t + (size_t)arow * 1024 + kg * 8;
    const unsigned short* wxrow = WxB + (size_t)pcol * 1024 + kg * 8;
    #pragma unroll 4
    for (int kk = 0; kk < 1024; kk += 64){
      bf16x8 a0 = cvt_f8(xrow + kk);
      bf16x8 b0 = *(const bf16x8*)(wxrow + kk);
      bf16x8 a1 = cvt_f8(xrow + kk + 32);
      bf16x8 b1 = *(const bf16x8*)(wxrow + kk + 32);
      acc0 = __builtin_amdgcn_mfma_f32_16x16x32_bf16(a0, b0, acc0, 0, 0, 0);
      acc1 = __builtin_amdgcn_mfma_f32_16x16x32_bf16(a1, b1, acc1, 0, 0, 0);
    }
  }
  f32x4 acc = acc0 + acc1;

  #pragma unroll
  for (int r = 0; r < 4; ++r){
    int brow = w * 16 + kg * 4 + r;
    glds[brow * 17 + rl] = acc[r];
  }
  __syncthreads();

  int b = tid >> 2, jj = tid & 3;
  int j = blk * 4 + jj;
  int pbase = blk * 16 + jj * 4;
  float gf = glds[b*17 + jj*4 + 0] + biasP[pbase + 0];
  float gi = glds[b*17 + jj*4 + 1] + biasP[pbase + 1];
  float go = glds[b*17 + jj*4 + 2] + biasP[pbase + 2];
  float gc = glds[b*17 + jj*4 + 3] + biasP[pbase + 3];
  float f  = fsigmoid(gf);
  float i_ = fsigmoid(gi);
  float o  = fsigmoid(go);
  float ct = ftanh(gc);
  float c_old = cbuf[b * H_DIM + j];
  float cn = f * c_old + i_ * ct;
  float hn = o * ftanh(cn);
  cbuf[b * H_DIM + j] = cn;
  h_out[b * H_DIM + j] = f2b(hn);
  out[((size_t)b * T_DIM + t) * H_DIM + j] = hn;
}

// ---------------- launch ----------------
extern "C" void kernel_launch(void* const* d_in, const int* in_sizes, int n_in,
                              void* d_out, int out_size, void* d_ws, size_t ws_size,
                              hipStream_t stream){
  (void)in_sizes; (void)n_in; (void)out_size;
  const float* emb = (const float*)d_in[0];
  const float* Wf  = (const float*)d_in[1];
  const float* bfv = (const float*)d_in[2];
  const float* Wi  = (const float*)d_in[3];
  const float* biv = (const float*)d_in[4];
  const float* Wo  = (const float*)d_in[5];
  const float* bov = (const float*)d_in[6];
  const float* Wc  = (const float*)d_in[7];
  const float* bcv = (const float*)d_in[8];
  float* out = (float*)d_out;

  char* ws = (char*)d_ws;
  size_t off = 0;
  auto alloc = [&](size_t bytes) -> void* {
    void* p = ws + off; off += (bytes + 255) & ~(size_t)255; return p;
  };
  unsigned short* WxB   = (unsigned short*)alloc((size_t)G_DIM * 1024 * 2);
  unsigned short* WhB   = (unsigned short*)alloc((size_t)G_DIM * 1024 * 2);
  float*          biasP = (float*)alloc((size_t)G_DIM * 4);
  unsigned short* h0    = (unsigned short*)alloc((size_t)B_DIM * H_DIM * 2);
  unsigned short* h1    = (unsigned short*)alloc((size_t)B_DIM * H_DIM * 2);
  float*          cglob = (float*)alloc((size_t)B_DIM * H_DIM * 4);
  int*            flags = (int*)alloc((size_t)4096 * 4);
  size_t base_end = off;

  // choose largest T-chunk whose embB(bf16) + xg(bf16) buffers fit in d_ws
  int Tc = 0;
  const int cands[6] = {512, 256, 128, 64, 32, 16};
  for (int ci = 0; ci < 6; ++ci){
    size_t need = base_end
                + (size_t)cands[ci] * B_DIM * E_DIM * 2   // embB chunk
                + (size_t)cands[ci] * B_DIM * G_DIM * 2   // xg chunk (bf16)
                + 4096;
    if (ws_size >= need){ Tc = cands[ci]; break; }
  }
  unsigned short* embB = nullptr;
  unsigned short* xgc  = nullptr;
  if (Tc > 0){
    embB = (unsigned short*)alloc((size_t)Tc * B_DIM * E_DIM * 2);
    xgc  = (unsigned short*)alloc((size_t)Tc * B_DIM * G_DIM * 2);
  }

  pack_weights<<<G_DIM, 256, 0, stream>>>(Wf, Wi, Wo, Wc, bfv, biv, bov, bcv, WxB, WhB, biasP);
  zero_state<<<256, 256, 0, stream>>>(h0, h1, cglob, flags);

  if (Tc > 0){
    for (int t0 = 0; t0 < T_DIM; t0 += Tc){
      conv_emb<<<2048, 256, 0, stream>>>(emb + (size_t)t0 * B_DIM * E_DIM, embB,
                                         (size_t)Tc * B_DIM * E_DIM / 4);
      gemm_xg<<<dim3(Tc * B_DIM / 128, G_DIM / 128), 256, 0, stream>>>(embB, WxB, xgc);
      lstm_scan<<<SBLK, 64, 0, stream>>>(WhB, xgc, biasP, h0, h1, cglob, out,
                                         flags, t0, t0 + Tc);
    }
  } else {
    // round-1 proven fallback: fused per-step kernels (no big buffers needed)
    for (int t = 0; t < T_DIM; ++t){
      const unsigned short* hin = (t & 1) ? h1 : h0;
      unsigned short*      hout = (t & 1) ? h0 : h1;
      lstm_step<<<256, 256, 0, stream>>>(
          WhB, WxB, emb + (size_t)t * B_DIM * E_DIM, hin, hout, cglob, biasP, out, t);
    }
  }
}

// Round 13
// 6070.903 us; speedup vs baseline: 1.0080x; 1.0065x over previous
//
#include <hip/hip_runtime.h>
#include <stdint.h>

#define T_DIM 512
#define B_DIM 64
#define E_DIM 1024
#define H_DIM 1024
#define G_DIM 4096   // 4*H, packed as p = j*4 + gate
#define SBLK 64      // scan blocks (1/CU by LDS; 2-phase pipeline)
#define CPB  64      // packed gate-cols per scan block (= 16 hidden units)

typedef short bf16x8 __attribute__((ext_vector_type(8)));
typedef float f32x4 __attribute__((ext_vector_type(4)));

__device__ __forceinline__ unsigned short f2b(float f){
  union{float f; unsigned u;} v; v.f = f;
  unsigned r = (v.u + 0x7FFFu + ((v.u >> 16) & 1u)) >> 16;  // RNE
  return (unsigned short)r;
}
__device__ __forceinline__ float b2f(unsigned short u){
  union{unsigned u; float f;} v; v.u = ((unsigned)u) << 16; return v.f;
}
__device__ __forceinline__ float fsigmoid(float x){
  return 1.f / (1.f + __expf(-x));
}
__device__ __forceinline__ float ftanh(float x){
  return 2.f / (1.f + __expf(-2.f * x)) - 1.f;
}

// ---- coherent-point (sc0 sc1) vmem helpers; all asm volatile so issue order
// ---- is program order (the vmcnt ledger depends on this).
template<int OFF>
__device__ __forceinline__ bf16x8 ld_h16(const unsigned short* p){
  bf16x8 r;
  asm volatile("global_load_dwordx4 %0, %1, off offset:%2 sc0 sc1"
               : "=v"(r) : "v"(p), "i"(OFF) : "memory");
  return r;
}
__device__ __forceinline__ bf16x8 ld_g16(const unsigned short* p){
  bf16x8 r;
  asm volatile("global_load_dwordx4 %0, %1, off"
               : "=v"(r) : "v"(p) : "memory");
  return r;
}
__device__ __forceinline__ void st_h16(unsigned short* p, bf16x8 v){
  asm volatile("global_store_dwordx4 %0, %1, off sc0 sc1"
               :: "v"(p), "v"(v) : "memory");
}
__device__ __forceinline__ void st_g16(float* p, f32x4 v){
  asm volatile("global_store_dwordx4 %0, %1, off"
               :: "v"(p), "v"(v) : "memory");
}
__device__ __forceinline__ void st_flag(int* p, int v){
  asm volatile("global_store_dword %0, %1, off sc0 sc1"
               :: "v"(p), "v"(v) : "memory");
}
__device__ __forceinline__ int ld_flag_nb(const int* p){
  int r;
  asm volatile("global_load_dword %0, %1, off sc0 sc1"
               : "=v"(r) : "v"(p) : "memory");
  return r;
}

// wait until <=N vmem outstanding; only DS_READ may be scheduled across
// (mask 0x100) — MFMA/VALU/VMEM pinned (rule #18).
#define WAITV(N) \
  asm volatile("s_waitcnt vmcnt(" #N ")" ::: "memory"); \
  __builtin_amdgcn_sched_barrier(0x100);

#define LD16(d0, d1, p0, p1, G) \
  d0[0]=ld_h16<((G)*8+0)*64>(p0); d0[1]=ld_h16<((G)*8+1)*64>(p0); \
  d0[2]=ld_h16<((G)*8+2)*64>(p0); d0[3]=ld_h16<((G)*8+3)*64>(p0); \
  d0[4]=ld_h16<((G)*8+4)*64>(p0); d0[5]=ld_h16<((G)*8+5)*64>(p0); \
  d0[6]=ld_h16<((G)*8+6)*64>(p0); d0[7]=ld_h16<((G)*8+7)*64>(p0); \
  d1[0]=ld_h16<((G)*8+0)*64>(p1); d1[1]=ld_h16<((G)*8+1)*64>(p1); \
  d1[2]=ld_h16<((G)*8+2)*64>(p1); d1[3]=ld_h16<((G)*8+3)*64>(p1); \
  d1[4]=ld_h16<((G)*8+4)*64>(p1); d1[5]=ld_h16<((G)*8+5)*64>(p1); \
  d1[6]=ld_h16<((G)*8+6)*64>(p1); d1[7]=ld_h16<((G)*8+7)*64>(p1);

// 8 kc-steps: 4 B-frags from LDS, each feeds 2 MFMAs (2 A row-tiles) — B reuse x2.
#define MFMA_GRP2(a0, a1, G) \
  { _Pragma("unroll") \
    for (int u = 0; u < 8; ++u){ \
      int kc_ = (G)*8 + u; \
      bf16x8 b0 = *(const bf16x8*)&Wl[((0*32 + kc_)*64 + lane)*8]; \
      bf16x8 b1 = *(const bf16x8*)&Wl[((1*32 + kc_)*64 + lane)*8]; \
      bf16x8 b2 = *(const bf16x8*)&Wl[((2*32 + kc_)*64 + lane)*8]; \
      bf16x8 b3 = *(const bf16x8*)&Wl[((3*32 + kc_)*64 + lane)*8]; \
      acc00 = __builtin_amdgcn_mfma_f32_16x16x32_bf16(a0[u], b0, acc00, 0,0,0); \
      acc01 = __builtin_amdgcn_mfma_f32_16x16x32_bf16(a0[u], b1, acc01, 0,0,0); \
      acc02 = __builtin_amdgcn_mfma_f32_16x16x32_bf16(a0[u], b2, acc02, 0,0,0); \
      acc03 = __builtin_amdgcn_mfma_f32_16x16x32_bf16(a0[u], b3, acc03, 0,0,0); \
      acc10 = __builtin_amdgcn_mfma_f32_16x16x32_bf16(a1[u], b0, acc10, 0,0,0); \
      acc11 = __builtin_amdgcn_mfma_f32_16x16x32_bf16(a1[u], b1, acc11, 0,0,0); \
      acc12 = __builtin_amdgcn_mfma_f32_16x16x32_bf16(a1[u], b2, acc12, 0,0,0); \
      acc13 = __builtin_amdgcn_mfma_f32_16x16x32_bf16(a1[u], b3, acc13, 0,0,0); \
    } }

// ---------------- prep kernels ----------------

__global__ void pack_weights(const float* __restrict__ Wf, const float* __restrict__ Wi,
                             const float* __restrict__ Wo, const float* __restrict__ Wc,
                             const float* __restrict__ bfv, const float* __restrict__ biv,
                             const float* __restrict__ bov, const float* __restrict__ bcv,
                             unsigned short* __restrict__ WxB, unsigned short* __restrict__ WhB,
                             float* __restrict__ biasP){
  int p = blockIdx.x;            // 0..4095
  int j = p >> 2, g = p & 3;
  const float* W    = (g==0)?Wf:(g==1)?Wi:(g==2)?Wo:Wc;
  const float* bsrc = (g==0)?bfv:(g==1)?biv:(g==2)?bov:bcv;
  const float* wrow = W + (size_t)j * 2048;
  int t = threadIdx.x;           // 256 threads, 4 k each
  float4 x = *(const float4*)(wrow + 4*t);
  float4 h = *(const float4*)(wrow + 1024 + 4*t);
  ushort4 xo = make_ushort4(f2b(x.x), f2b(x.y), f2b(x.z), f2b(x.w));
  ushort4 ho = make_ushort4(f2b(h.x), f2b(h.y), f2b(h.z), f2b(h.w));
  *(ushort4*)&WxB[(size_t)p*1024 + 4*t] = xo;
  *(ushort4*)&WhB[(size_t)p*1024 + 4*t] = ho;
  if (t == 0) biasP[p] = bsrc[j];
}

__global__ void conv_emb(const float* __restrict__ emb, unsigned short* __restrict__ embB,
                         size_t n4){
  for (size_t i = (size_t)blockIdx.x * blockDim.x + threadIdx.x; i < n4;
       i += (size_t)gridDim.x * blockDim.x){
    float4 v = ((const float4*)emb)[i];
    ((ushort4*)embB)[i] = make_ushort4(f2b(v.x), f2b(v.y), f2b(v.z), f2b(v.w));
  }
}

__global__ void zero_state(unsigned short* __restrict__ h0, unsigned short* __restrict__ h1,
                           float* __restrict__ c, int* __restrict__ flags){
  int i = blockIdx.x * blockDim.x + threadIdx.x;  // 65536 threads exactly
  h0[i] = 0; h1[i] = 0; c[i] = 0.f;
  if (i < 4096) flags[i] = 0;
}

// ---------------- big GEMM: xg_chunk = embB @ WxB^T (bf16 out) ----------------
__launch_bounds__(256)
__global__ void gemm_xg(const unsigned short* __restrict__ A,
                        const unsigned short* __restrict__ B,
                        unsigned short* __restrict__ C){
  __shared__ unsigned short Al[128*32];
  __shared__ unsigned short Bl[128*32];
  int m0 = blockIdx.x * 128, n0 = blockIdx.y * 128;
  int tid = threadIdx.x, lane = tid & 63, wid = tid >> 6;
  int mblk = (wid >> 1) * 64, nblk = (wid & 1) * 64;
  int rl = lane & 15, kg = lane >> 4;
  f32x4 acc[4][4] = {};

  for (int kk = 0; kk < 1024; kk += 32){
    {
      int c0 = tid, c1 = tid + 256;
      int r = c0 >> 2, g = c0 & 3, s = g ^ ((r >> 1) & 3);
      *(uint4*)&Al[r*32 + s*8] = *(const uint4*)&A[(size_t)(m0 + r)*1024 + kk + g*8];
      *(uint4*)&Bl[r*32 + s*8] = *(const uint4*)&B[(size_t)(n0 + r)*1024 + kk + g*8];
      r = c1 >> 2; g = c1 & 3; s = g ^ ((r >> 1) & 3);
      *(uint4*)&Al[r*32 + s*8] = *(const uint4*)&A[(size_t)(m0 + r)*1024 + kk + g*8];
      *(uint4*)&Bl[r*32 + s*8] = *(const uint4*)&B[(size_t)(n0 + r)*1024 + kk + g*8];
    }
    __syncthreads();
    bf16x8 a[4], b[4];
    #pragma unroll
    for (int mf = 0; mf < 4; ++mf){
      int r = mblk + mf*16 + rl;
      a[mf] = *(const bf16x8*)&Al[r*32 + (kg ^ ((r >> 1) & 3))*8];
    }
    #pragma unroll
    for (int nf = 0; nf < 4; ++nf){
      int r = nblk + nf*16 + rl;
      b[nf] = *(const bf16x8*)&Bl[r*32 + (kg ^ ((r >> 1) & 3))*8];
    }
    #pragma unroll
    for (int mf = 0; mf < 4; ++mf)
      #pragma unroll
      for (int nf = 0; nf < 4; ++nf)
        acc[mf][nf] = __builtin_amdgcn_mfma_f32_16x16x32_bf16(a[mf], b[nf], acc[mf][nf], 0, 0, 0);
    __syncthreads();
  }

  // C/D layout (m89-verified): col = lane&15, row = (lane>>4)*4 + reg
  int rq = kg * 4;
  #pragma unroll
  for (int mf = 0; mf < 4; ++mf)
    #pragma unroll
    for (int nf = 0; nf < 4; ++nf){
      int col = n0 + nblk + nf*16 + rl;
      #pragma unroll
      for (int r = 0; r < 4; ++r){
        int row = m0 + mblk + mf*16 + rq + r;
        C[(size_t)row * G_DIM + col] = f2b(acc[mf][nf][r]);
      }
    }
}

// ---------------- persistent recurrent scan: 2-phase pipeline ----------------
// 64 blocks x 64 threads (1 wave), 1 block/CU (137 KB LDS). Block cs owns
// pcols cs*64..+64 (16 hidden units). Phase g in {0,1} = batch rows g*32..+32
// — the two phases are INDEPENDENT LSTM instances, so phase g's L3 sync
// window hides under phase g^1's compute. Flags discovered via non-blocking
// deferred polls (issued mid-phase, checked at phase end); counted-vmcnt
// ledger spans phase boundaries (all vmem is asm volatile -> program order).
// flag[blk][g] = t+1  <=>  "blk stored h(g,t) (ack'd) AND finished reading
// h(g,t-1)" — same 2-slot ping-pong safety proof as r6.
#define PHASE(G, t)                                                            \
{                                                                              \
  /* entry outstanding: [H 1][xg 4][A32: P,Q][out 2] (H/out absent in         \
     prologue/slow-path variants -- WAITV constants still exact) */           \
  WAITV(18);   /* H + xg4 + A-g0 complete -> safe to publish prev flag */     \
  st_flag(&flags[(cs*2 + ((G)^1))*16], ((G)==0) ? (t) : ((t)+1));              \
  f32x4 acc00={},acc01={},acc02={},acc03={},acc10={},acc11={},acc12={},acc13={};\
  MFMA_GRP2(P0, P1, 0);                                                        \
  LD16(P0, P1, ap0, ap1, 2);   /* current phase, groups 2,3 */                 \
  LD16(R0, R1, ap0, ap1, 3);                                                   \
  pv = ld_flag_nb(&flags[(lane*2 + ((G)^1))*16]);                              \
  WAITV(35);   /* A-g1 complete */                                             \
  MFMA_GRP2(Q0, Q1, 1);                                                        \
  WAITV(17);   /* A-g2 complete */                                             \
  MFMA_GRP2(P0, P1, 2);                                                        \
  WAITV(1);    /* A-g3 complete (poll may linger) */                           \
  MFMA_GRP2(R0, R1, 3);                                                        \
  asm volatile("s_waitcnt lgkmcnt(0)" ::: "memory");                           \
  { int r0 = kg*4;                                                             \
    _Pragma("unroll") for (int rg = 0; rg < 4; ++rg){                          \
      gl[r0+rg][ 0+rl]=acc00[rg]; gl[r0+rg][16+rl]=acc01[rg];                  \
      gl[r0+rg][32+rl]=acc02[rg]; gl[r0+rg][48+rl]=acc03[rg];                  \
      gl[16+r0+rg][ 0+rl]=acc10[rg]; gl[16+r0+rg][16+rl]=acc11[rg];            \
      gl[16+r0+rg][32+rl]=acc12[rg]; gl[16+r0+rg][48+rl]=acc13[rg]; } }        \
  asm volatile("s_waitcnt lgkmcnt(0)" ::: "memory");                           \
  __builtin_amdgcn_sched_barrier(0);                                           \
  union{ unsigned short us[8]; bf16x8 v; } hp;                                 \
  f32x4 ovA, ovB;                                                              \
  _Pragma("unroll") for (int m = 0; m < 8; ++m){                               \
    f32x4 gv = *(const f32x4*)&gl[bb][q*32 + m*4];                             \
    _Pragma("unroll") for (int e = 0; e < 4; ++e)                              \
      gv[e] += b2f((unsigned short)xr[m>>1][(m&1)*4 + e]) + bias8[m][e];       \
    float f_ = fsigmoid(gv[0]), i_ = fsigmoid(gv[1]);                          \
    float o_ = fsigmoid(gv[2]), ct_ = ftanh(gv[3]);                            \
    float c_ = f_*cvs[G][m] + i_*ct_; cvs[G][m] = c_;                          \
    float hn = o_*ftanh(c_);                                                   \
    hp.us[m] = f2b(hn);                                                        \
    if (m < 4) ovA[m] = hn; else ovB[m-4] = hn;                                \
  }                                                                            \
  { unsigned short* hout = ((t)&1) ? hb0 : hb1;                                \
    st_h16(&hout[(size_t)((G)*32 + bb)*H_DIM + cs*16 + q*8], hp.v); }          \
  WAITV(1);    /* poll value landed (H may linger) */                          \
  __builtin_amdgcn_sched_barrier(0);                                           \
  { const int tn = ((G)==0) ? (t) : ((t)+1);                                   \
    if (__any(pv < tn)){   /* slow path: blocking spin (drains vmcnt) */       \
      const int* fp = &flags[(lane*2 + ((G)^1))*16];                           \
      while (__any(__hip_atomic_load(fp, __ATOMIC_RELAXED,                     \
                                     __HIP_MEMORY_SCOPE_AGENT) < tn))          \
        __builtin_amdgcn_s_sleep(1);                                           \
    }                                                                          \
    const unsigned short* hinN = ((tn)&1) ? hb1 : hb0;                         \
    ap0 = hinN + (size_t)((((G)^1)*32) + rl)*1024 + kg*8;                      \
    ap1 = ap0 + (size_t)16*1024;                                               \
    int txg = (tn < t1) ? tn : (t1 - 1);                                       \
    const unsigned short* xgpN = xgc + ((size_t)(txg - t0)*B_DIM               \
        + (((G)^1)*32 + bb))*G_DIM + cs*64 + q*32;                             \
    xr[0] = ld_g16(xgpN);      xr[1] = ld_g16(xgpN + 8);                       \
    xr[2] = ld_g16(xgpN + 16); xr[3] = ld_g16(xgpN + 24);                      \
    LD16(P0, P1, ap0, ap1, 0);                                                 \
    LD16(Q0, Q1, ap0, ap1, 1);                                                 \
    st_g16(&out[((size_t)((G)*32 + bb)*T_DIM + (t))*H_DIM + cs*16 + q*8], ovA);\
    st_g16(&out[((size_t)((G)*32 + bb)*T_DIM + (t))*H_DIM + cs*16 + q*8 + 4], ovB);\
  }                                                                            \
}

__launch_bounds__(64, 1)
__global__ void lstm_scan(const unsigned short* __restrict__ WhB,
                          const unsigned short* __restrict__ xgc,  // bf16 [t1-t0][B][G]
                          const float* __restrict__ biasP,
                          unsigned short* __restrict__ hb0,
                          unsigned short* __restrict__ hb1,
                          float* __restrict__ cglob,
                          float* __restrict__ out,
                          int* __restrict__ flags,
                          int t0, int t1){
  __shared__ unsigned short Wl[4*32*64*8];   // 128 KB frag-major [ct][kc][lane][8]
  __shared__ float gl[32][68];               // 8.7 KB gate staging (+pad)

  const int tid = threadIdx.x;               // 0..63 (one wave)
  const int cs = blockIdx.x;                 // 0..63
  const int lane = tid;
  const int rl = lane & 15, kg = lane >> 4;

  // One-time: stage Wh fragments (A/B share the same (lane,elem)->k map)
  for (int idx = tid; idx < 4*32*64; idx += 64){
    int ct = idx >> 11, kc = (idx >> 6) & 31, l = idx & 63;
    int col = cs*CPB + ct*16 + (l & 15);
    int k   = kc*32 + (l >> 4)*8;
    *(bf16x8*)&Wl[idx*8] = *(const bf16x8*)&WhB[(size_t)col*1024 + k];
  }

  // elementwise mapping: thread -> (local row bb in phase, unit-half q)
  const int bb = tid >> 1, q = tid & 1;      // 8 units: cs*16 + q*8 ..
  f32x4 bias8[8];
  #pragma unroll
  for (int m = 0; m < 8; ++m)
    bias8[m] = *(const f32x4*)&biasP[cs*64 + q*32 + m*4];
  float cvs[2][8];
  #pragma unroll
  for (int g = 0; g < 2; ++g){
    f32x4 lo = *(const f32x4*)&cglob[(size_t)(g*32 + bb)*H_DIM + cs*16 + q*8];
    f32x4 hi = *(const f32x4*)&cglob[(size_t)(g*32 + bb)*H_DIM + cs*16 + q*8 + 4];
    #pragma unroll
    for (int e = 0; e < 4; ++e){ cvs[g][e] = lo[e]; cvs[g][4+e] = hi[e]; }
  }

  __syncthreads();  // Wl staged (also drains all prior vmem)

  // prologue: blocking wait for phase (0, t0)'s producers
  {
    const int* fp = &flags[(lane*2 + 0)*16];
    while (__any(__hip_atomic_load(fp, __ATOMIC_RELAXED,
                                   __HIP_MEMORY_SCOPE_AGENT) < t0))
      __builtin_amdgcn_s_sleep(1);
  }

  // loop-carried state
  bf16x8 P0[8], P1[8], Q0[8], Q1[8], R0[8], R1[8];
  bf16x8 xr[4];
  const unsigned short* ap0;
  const unsigned short* ap1;
  int pv = 0x7FFFFFFF;

  // prologue issues — ledger shape matches steady state: [d1][xg4][A32][d2 d3]
  {
    const unsigned short* hin0 = (t0 & 1) ? hb1 : hb0;
    ap0 = hin0 + (size_t)rl*1024 + kg*8;
    ap1 = ap0 + (size_t)16*1024;
    bf16x8 d1 = ld_g16(xgc);                       // dummy (H slot)
    const unsigned short* xgp0 = xgc + ((size_t)bb)*G_DIM + cs*64 + q*32;
    xr[0] = ld_g16(xgp0);      xr[1] = ld_g16(xgp0 + 8);
    xr[2] = ld_g16(xgp0 + 16); xr[3] = ld_g16(xgp0 + 24);
    LD16(P0, P1, ap0, ap1, 0);
    LD16(Q0, Q1, ap0, ap1, 1);
    bf16x8 d2 = ld_g16(xgc); bf16x8 d3 = ld_g16(xgc + 8);   // dummies (out slots)
    asm volatile("" :: "v"(d1), "v"(d2), "v"(d3));
  }

  for (int t = t0; t < t1; ++t){
    PHASE(0, t);
    PHASE(1, t);
  }

  // epilogue: drain everything, publish final flag for chunk continuity
  WAITV(0);
  st_flag(&flags[(cs*2 + 1)*16], t1);
  #pragma unroll
  for (int g = 0; g < 2; ++g){
    f32x4 lo, hi;
    #pragma unroll
    for (int e = 0; e < 4; ++e){ lo[e] = cvs[g][e]; hi[e] = cvs[g][4+e]; }
    *(f32x4*)&cglob[(size_t)(g*32 + bb)*H_DIM + cs*16 + q*8] = lo;
    *(f32x4*)&cglob[(size_t)(g*32 + bb)*H_DIM + cs*16 + q*8 + 4] = hi;
  }
}

// ---------------- round-1 proven fallback: per-step launched kernel ----------------
__device__ __forceinline__ bf16x8 cvt_f8(const float* p){
  float4 u = *(const float4*)p;
  float4 v = *(const float4*)(p + 4);
  bf16x8 r;
  r[0] = (short)f2b(u.x); r[1] = (short)f2b(u.y); r[2] = (short)f2b(u.z); r[3] = (short)f2b(u.w);
  r[4] = (short)f2b(v.x); r[5] = (short)f2b(v.y); r[6] = (short)f2b(v.z); r[7] = (short)f2b(v.w);
  return r;
}

__launch_bounds__(256)
__global__ void lstm_step(const unsigned short* __restrict__ WhB,
                          const unsigned short* __restrict__ WxB,
                          const float* __restrict__ emb_t,
                          const unsigned short* __restrict__ h_in,
                          unsigned short* __restrict__ h_out,
                          float* __restrict__ cbuf,
                          const float* __restrict__ biasP,
                          float* __restrict__ out, int t){
  __shared__ float glds[64 * 17];
  int tid = threadIdx.x, lane = tid & 63, w = tid >> 6;
  int blk = blockIdx.x;
  int rl = lane & 15, kg = lane >> 4;
  int arow = w * 16 + rl;
  int pcol = blk * 16 + rl;

  f32x4 acc0 = {}, acc1 = {};
  const unsigned short* hrow = h_in + (size_t)arow * 1024 + kg * 8;
  const unsigned short* wrow = WhB + (size_t)pcol * 1024 + kg * 8;
  #pragma unroll 4
  for (int kk = 0; kk < 1024; kk += 64){
    bf16x8 a0 = *(const bf16x8*)(hrow + kk);
    bf16x8 b0 = *(const bf16x8*)(wrow + kk);
    bf16x8 a1 = *(const bf16x8*)(hrow + kk + 32);
    bf16x8 b1 = *(const bf16x8*)(wrow + kk + 32);
    acc0 = __builtin_amdgcn_mfma_f32_16x16x32_bf16(a0, b0, acc0, 0, 0, 0);
    acc1 = __builtin_amdgcn_mfma_f32_16x16x32_bf16(a1, b1, acc1, 0, 0, 0);
  }
  {
    const float* xrow = emb_t + (size_t)arow * 1024 + kg * 8;
    const unsigned short* wxrow = WxB + (size_t)pcol * 1024 + kg * 8;
    #pragma unroll 4
    for (int kk = 0; kk < 1024; kk += 64){
      bf16x8 a0 = cvt_f8(xrow + kk);
      bf16x8 b0 = *(const bf16x8*)(wxrow + kk);
      bf16x8 a1 = cvt_f8(xrow + kk + 32);
      bf16x8 b1 = *(const bf16x8*)(wxrow + kk + 32);
      acc0 = __builtin_amdgcn_mfma_f32_16x16x32_bf16(a0, b0, acc0, 0, 0, 0);
      acc1 = __builtin_amdgcn_mfma_f32_16x16x32_bf16(a1, b1, acc1, 0, 0, 0);
    }
  }
  f32x4 acc = acc0 + acc1;

  #pragma unroll
  for (int r = 0; r < 4; ++r){
    int brow = w * 16 + kg * 4 + r;
    glds[brow * 17 + rl] = acc[r];
  }
  __syncthreads();

  int b = tid >> 2, jj = tid & 3;
  int j = blk * 4 + jj;
  int pbase = blk * 16 + jj * 4;
  float gf = glds[b*17 + jj*4 + 0] + biasP[pbase + 0];
  float gi = glds[b*17 + jj*4 + 1] + biasP[pbase + 1];
  float go = glds[b*17 + jj*4 + 2] + biasP[pbase + 2];
  float gc = glds[b*17 + jj*4 + 3] + biasP[pbase + 3];
  float f  = fsigmoid(gf);
  float i_ = fsigmoid(gi);
  float o  = fsigmoid(go);
  float ct = ftanh(gc);
  float c_old = cbuf[b * H_DIM + j];
  float cn = f * c_old + i_ * ct;
  float hn = o * ftanh(cn);
  cbuf[b * H_DIM + j] = cn;
  h_out[b * H_DIM + j] = f2b(hn);
  out[((size_t)b * T_DIM + t) * H_DIM + j] = hn;
}

// ---------------- launch ----------------
extern "C" void kernel_launch(void* const* d_in, const int* in_sizes, int n_in,
                              void* d_out, int out_size, void* d_ws, size_t ws_size,
                              hipStream_t stream){
  (void)in_sizes; (void)n_in; (void)out_size;
  const float* emb = (const float*)d_in[0];
  const float* Wf  = (const float*)d_in[1];
  const float* bfv = (const float*)d_in[2];
  const float* Wi  = (const float*)d_in[3];
  const float* biv = (const float*)d_in[4];
  const float* Wo  = (const float*)d_in[5];
  const float* bov = (const float*)d_in[6];
  const float* Wc  = (const float*)d_in[7];
  const float* bcv = (const float*)d_in[8];
  float* out = (float*)d_out;

  char* ws = (char*)d_ws;
  size_t off = 0;
  auto alloc = [&](size_t bytes) -> void* {
    void* p = ws + off; off += (bytes + 255) & ~(size_t)255; return p;
  };
  unsigned short* WxB   = (unsigned short*)alloc((size_t)G_DIM * 1024 * 2);
  unsigned short* WhB   = (unsigned short*)alloc((size_t)G_DIM * 1024 * 2);
  float*          biasP = (float*)alloc((size_t)G_DIM * 4);
  unsigned short* h0    = (unsigned short*)alloc((size_t)B_DIM * H_DIM * 2);
  unsigned short* h1    = (unsigned short*)alloc((size_t)B_DIM * H_DIM * 2);
  float*          cglob = (float*)alloc((size_t)B_DIM * H_DIM * 4);
  int*            flags = (int*)alloc((size_t)4096 * 4);
  size_t base_end = off;

  // choose largest T-chunk whose embB(bf16) + xg(bf16) buffers fit in d_ws
  int Tc = 0;
  const int cands[6] = {512, 256, 128, 64, 32, 16};
  for (int ci = 0; ci < 6; ++ci){
    size_t need = base_end
                + (size_t)cands[ci] * B_DIM * E_DIM * 2   // embB chunk
                + (size_t)cands[ci] * B_DIM * G_DIM * 2   // xg chunk (bf16)
                + 4096;
    if (ws_size >= need){ Tc = cands[ci]; break; }
  }
  unsigned short* embB = nullptr;
  unsigned short* xgc  = nullptr;
  if (Tc > 0){
    embB = (unsigned short*)alloc((size_t)Tc * B_DIM * E_DIM * 2);
    xgc  = (unsigned short*)alloc((size_t)Tc * B_DIM * G_DIM * 2);
  }

  pack_weights<<<G_DIM, 256, 0, stream>>>(Wf, Wi, Wo, Wc, bfv, biv, bov, bcv, WxB, WhB, biasP);
  zero_state<<<256, 256, 0, stream>>>(h0, h1, cglob, flags);

  if (Tc > 0){
    for (int t0 = 0; t0 < T_DIM; t0 += Tc){
      conv_emb<<<2048, 256, 0, stream>>>(emb + (size_t)t0 * B_DIM * E_DIM, embB,
                                         (size_t)Tc * B_DIM * E_DIM / 4);
      gemm_xg<<<dim3(Tc * B_DIM / 128, G_DIM / 128), 256, 0, stream>>>(embB, WxB, xgc);
      lstm_scan<<<SBLK, 64, 0, stream>>>(WhB, xgc, biasP, h0, h1, cglob, out,
                                         flags, t0, t0 + Tc);
    }
  } else {
    // round-1 proven fallback: fused per-step kernels (no big buffers needed)
    for (int t = 0; t < T_DIM; ++t){
      const unsigned short* hin = (t & 1) ? h1 : h0;
      unsigned short*      hout = (t & 1) ? h0 : h1;
      lstm_step<<<256, 256, 0, stream>>>(
          WhB, WxB, emb + (size_t)t * B_DIM * E_DIM, hin, hout, cglob, biasP, out, t);
    }
  }
}